// Round 7
// baseline (89.822 us; speedup 1.0000x reference)
//
#include <hip/hip_runtime.h>
#include <math.h>

// diag-RTRL, round 7: ONE kernel, no split-K, no workspace, no 2nd dispatch.
//   s      = tanh(0.9*u + x@W)         [32,1024]
//   u_new  = 0.9*u + x@W               [32,1024]
//   E_new  = 0.9*E + x[:,:,None]       [32,1024,1024]  (268 MB stream, dominates)
//
// Round-6 post-mortem: store flavor (nt vs plain) is a non-lever (FETCH 68MB,
// WRITE 135MB identical); fillBufferAligned hits 6.88 TB/s at 9.6% occupancy
// so BW needs few waves; the ~10us gap over the 32us HBM floor is k2 + launch
// gap + ws round-trip. This round removes all three:
//  * 32 GEMM blocks, each a 32-col j-tile with FULL K=1024: 4 acc/thread,
//    W read directly from L2 (4MB, hot every replay), x staged in 8KB LDS
//    chunks. Latency stalls are filled by co-resident stream waves; block
//    finishes ~15-20us < ~34us stream, writes s/u_new directly.
//  * 2048 stream blocks: identical to round-4 stream (NT store, ILP-4),
//    but x via SGPR-uniform index sb*16+t -> scalar load (no VMEM for x).
//  * grid 2080, single dispatch, d_ws unused.

#define BETA 0.9f

constexpr int Bb   = 32;
constexpr int D_IN = 1024;
constexpr int D_H  = 1024;

constexpr int THREADS       = 256;
constexpr int GEMM_BLOCKS   = 32;    // j-tiles of 32 cols, full-K
constexpr int STREAM_BLOCKS = 2048;  // 2048 * 16 trips * 256 f4 = full E
constexpr int TRIPS         = 16;
constexpr int KCH           = 64;    // x rows staged in LDS per chunk

typedef float f4 __attribute__((ext_vector_type(4)));

__global__ __launch_bounds__(THREADS, 8) void rtrl_fused(
    const float* __restrict__ x,   // [32,1024]
    const float* __restrict__ W,   // [1024,1024]
    const float* __restrict__ u,   // [32,1024]
    const float* __restrict__ E,   // [32,1024,1024]
    float* __restrict__ out)       // [s | u_new | E_new]
{
    __shared__ float xs[Bb][KCH];  // 8 KB (unused by stream blocks)

    const int blk = blockIdx.x;
    const int tid = threadIdx.x;

    if (blk < GEMM_BLOCKS) {
        // ---------- GEMM + tanh: j-tile [blk*32, +32), all 32 b, full K ----
        const int j0 = blk * 32;
        const int jc = tid & 31;       // col within tile
        const int bg = tid >> 5;       // 0..7 -> 4 batch rows each

        const f4* __restrict__ x4 = (const f4*)x;   // row stride 256 f4
        float a0 = 0.f, a1 = 0.f, a2 = 0.f, a3 = 0.f;

        for (int ko = 0; ko < D_IN / KCH; ++ko) {   // 16 chunks of 64 k-rows
            // cooperative x-chunk load: 32 b x 64 k = 512 f4, 2 per thread
            f4* xs4 = (f4*)xs;
            #pragma unroll
            for (int p = 0; p < 2; ++p) {
                const int idx = tid + p * 256;      // 0..511
                xs4[idx] = x4[(idx >> 4) * (D_IN / 4) + ko * (KCH / 4) + (idx & 15)];
            }
            __syncthreads();

            // W straight from L2: lanes jc=0..31 consecutive -> 128B/half-wave
            const float* __restrict__ Wp = W + (ko * KCH) * D_H + j0 + jc;
            #pragma unroll 8
            for (int i = 0; i < KCH; ++i) {
                const float wv = Wp[i * D_H];
                a0 = fmaf(xs[bg * 4 + 0][i], wv, a0);   // LDS broadcast reads
                a1 = fmaf(xs[bg * 4 + 1][i], wv, a1);
                a2 = fmaf(xs[bg * 4 + 2][i], wv, a2);
                a3 = fmaf(xs[bg * 4 + 3][i], wv, a3);
            }
            __syncthreads();
        }

        const float acc[4] = {a0, a1, a2, a3};
        #pragma unroll
        for (int r = 0; r < 4; ++r) {
            const int t  = (bg * 4 + r) * D_H + j0 + jc;
            const float un = BETA * u[t] + acc[r];
            out[t]            = tanhf(un);   // s
            out[Bb * D_H + t] = un;          // u_new
        }
    } else {
        // ---------- E stream: contiguous 64KB region per block ----------
        const int sb = blk - GEMM_BLOCKS;
        const f4* __restrict__ E4 = (const f4*)E;
        f4* __restrict__ O4 = (f4*)(out + 2 * Bb * D_H);

        const int xbase = sb * TRIPS;              // SGPR-uniform x index base
        int v = sb * (TRIPS * THREADS) + tid;

        #pragma unroll
        for (int g = 0; g < TRIPS / 4; ++g) {      // 4 groups, ILP-4
            f4 e0 = E4[v];
            f4 e1 = E4[v + 256];
            f4 e2 = E4[v + 512];
            f4 e3 = E4[v + 768];
            const float x0 = x[xbase + g * 4 + 0]; // scalar (SGPR) loads
            const float x1 = x[xbase + g * 4 + 1];
            const float x2 = x[xbase + g * 4 + 2];
            const float x3 = x[xbase + g * 4 + 3];
            __builtin_nontemporal_store(e0 * BETA + x0, &O4[v]);
            __builtin_nontemporal_store(e1 * BETA + x1, &O4[v + 256]);
            __builtin_nontemporal_store(e2 * BETA + x2, &O4[v + 512]);
            __builtin_nontemporal_store(e3 * BETA + x3, &O4[v + 768]);
            v += 1024;
        }
    }
}

extern "C" void kernel_launch(void* const* d_in, const int* in_sizes, int n_in,
                              void* d_out, int out_size, void* d_ws, size_t ws_size,
                              hipStream_t stream) {
    const float* x = (const float*)d_in[0];
    const float* W = (const float*)d_in[1];
    const float* u = (const float*)d_in[2];
    const float* E = (const float*)d_in[3];
    float* out = (float*)d_out;

    rtrl_fused<<<GEMM_BLOCKS + STREAM_BLOCKS, THREADS, 0, stream>>>(x, W, u, E, out);
}

// Round 8
// 83.470 us; speedup vs baseline: 1.0761x; 1.0761x over previous
//
#include <hip/hip_runtime.h>
#include <math.h>

// diag-RTRL, round 8: r4 split-K structure with k2 FUSED via arrival counter.
//   s      = tanh(0.9*u + x@W)         [32,1024]
//   u_new  = 0.9*u + x@W               [32,1024]
//   E_new  = 0.9*E + x[:,:,None]       [32,1024,1024]  (268 MB stream, dominates)
//
// History: r4 (split-K 512 tile blocks + 2048-block stream + separate k2
// reduce) = 48.6us best. r7 (32 full-K GEMM blocks) = 89.8us -> GEMM must be
// split-K wide or it's the critical path. Store flavor (nt/plain/sc1) = dead
// lever. 203 MB real HBM traffic -> ~32us floor; k2 dispatch costs ~4-6us.
// This round: remove k2. Tile blocks release partials with
// __threadfence()+atomicAdd (device scope, Guideline-16 path) BEFORE their
// stream trips; the last 128 stream blocks reduce after their stream work
// (arrivals complete ~25us before they get there -> near-zero spin).
// Counter zeroed per call by 4-byte hipMemsetAsync (graph-capturable).
// Fallback to the proven two-kernel r4 path if ws_size lacks the 4 bytes.

#define BETA 0.9f

constexpr int Bb   = 32;
constexpr int D_IN = 1024;
constexpr int D_H  = 1024;

constexpr int THREADS    = 256;
constexpr int KSPLIT     = 32;                 // 32 k-chunks of 32 rows
constexpr int JTILES     = 16;                 // 16 j-tiles of 64 cols
constexpr int GEMM_TILES = KSPLIT * JTILES;    // 512 blocks carry a tile
constexpr int GRID1      = 2048;
constexpr int TRIPS_G    = 13;                 // E trips for tile-carrying blocks
constexpr int TRIPS_E    = 17;                 // E trips for plain blocks
constexpr int RED_BLOCKS = 128;                // last 128 blocks also reduce
// 512*13 + 1536*17 = 32768 trips * 256 f4 = 8,388,608 f4 = full E.
constexpr size_t PART_BYTES = (size_t)KSPLIT * Bb * D_H * sizeof(float); // 4 MB

typedef float f4 __attribute__((ext_vector_type(4)));

template <bool FUSED>
__global__ __launch_bounds__(THREADS) void rtrl_k1(
    const float* __restrict__ x,   // [32,1024]
    const float* __restrict__ W,   // [1024,1024]
    const float* __restrict__ u,   // [32,1024]
    const float* __restrict__ E,   // [32,1024,1024]
    float* __restrict__ out,       // [s | u_new | E_new]
    float* __restrict__ ws,        // [KSPLIT][32][1024] partials
    unsigned* __restrict__ cnt)    // arrival counter (zeroed per call)
{
    __shared__ float Wt[32][64];   // 8 KB  : k-chunk x j-tile of W
    __shared__ float xs[32][32];   // 4 KB  : all b x k-chunk of x

    const int blk = blockIdx.x;
    const int tid = threadIdx.x;

    if (blk < GEMM_TILES) {
        // ---------- one GEMM tile: kt = k-chunk, jt = j-tile ----------
        const int kt = blk >> 4;          // 0..31
        const int jt = blk & 15;          // 0..15
        const int i0 = kt * 32;
        const int j0 = jt * 64;

        const f4* __restrict__ W4 = (const f4*)W;   // row stride 256 f4
        const f4* __restrict__ x4 = (const f4*)x;   // row stride 256 f4

        // load W tile: 32 rows x 16 f4 = 512 f4, 2 per thread
        {
            f4* Wt4 = (f4*)Wt;
            #pragma unroll
            for (int p = 0; p < 2; ++p) {
                const int idx = tid + p * 256;
                const int row = idx >> 4, c4 = idx & 15;
                Wt4[row * 16 + c4] = W4[(i0 + row) * 256 + (j0 >> 2) + c4];
            }
        }
        // load x tile: 32 b x 8 f4 = 256 f4, 1 per thread
        {
            f4* xs4 = (f4*)xs;
            const int row = tid >> 3, c4 = tid & 7;
            xs4[row * 8 + c4] = x4[row * 256 + (i0 >> 2) + c4];
        }
        __syncthreads();

        // compute: each thread -> 8 batch rows, one j column
        const int bg = tid >> 6;          // wave-uniform: 8-batch group
        const int jc = tid & 63;          // column within tile
        float a0=0,a1=0,a2=0,a3=0,a4=0,a5=0,a6=0,a7=0;
        #pragma unroll 8
        for (int i = 0; i < 32; ++i) {
            const float wv = Wt[i][jc];   // 64 consecutive lanes: conflict-free
            a0 = fmaf(xs[bg*8+0][i], wv, a0);  // xs reads broadcast (uniform addr)
            a1 = fmaf(xs[bg*8+1][i], wv, a1);
            a2 = fmaf(xs[bg*8+2][i], wv, a2);
            a3 = fmaf(xs[bg*8+3][i], wv, a3);
            a4 = fmaf(xs[bg*8+4][i], wv, a4);
            a5 = fmaf(xs[bg*8+5][i], wv, a5);
            a6 = fmaf(xs[bg*8+6][i], wv, a6);
            a7 = fmaf(xs[bg*8+7][i], wv, a7);
        }
        float acc[8] = {a0,a1,a2,a3,a4,a5,a6,a7};
        #pragma unroll
        for (int bb = 0; bb < 8; ++bb) {
            const int b = bg * 8 + bb;
            ws[(kt * Bb + b) * D_H + j0 + jc] = acc[bb];   // coalesced
        }

        if (FUSED) {
            __syncthreads();              // all partial stores issued
            if (tid == 0) {
                __threadfence();          // device-scope release (wb L2)
                atomicAdd(cnt, 1u);       // publish arrival
            }
        }
    }

    // ---------- E stream: contiguous region per block ----------
    {
        const f4* __restrict__ E4 = (const f4*)E;
        f4* __restrict__ O4 = (f4*)(out + 2 * Bb * D_H);

        const int ntrips = (blk < GEMM_TILES) ? TRIPS_G : TRIPS_E;
        const int r0     = (blk < GEMM_TILES)
                         ? blk * (TRIPS_G * THREADS)
                         : GEMM_TILES * (TRIPS_G * THREADS) + (blk - GEMM_TILES) * (TRIPS_E * THREADS);

        int v = r0 + tid;
        int t = 0;
        for (; t + 4 <= ntrips; t += 4) {     // 4 loads in flight
            f4 e0 = E4[v];
            f4 e1 = E4[v + 256];
            f4 e2 = E4[v + 512];
            f4 e3 = E4[v + 768];
            const float x0 = x[v >> 8];
            const float x1 = x[(v + 256) >> 8];
            const float x2 = x[(v + 512) >> 8];
            const float x3 = x[(v + 768) >> 8];
            __builtin_nontemporal_store(e0 * BETA + x0, &O4[v]);
            __builtin_nontemporal_store(e1 * BETA + x1, &O4[v + 256]);
            __builtin_nontemporal_store(e2 * BETA + x2, &O4[v + 512]);
            __builtin_nontemporal_store(e3 * BETA + x3, &O4[v + 768]);
            v += 1024;
        }
        for (; t < ntrips; ++t) {
            f4 e = E4[v];
            const float xv = x[v >> 8];
            __builtin_nontemporal_store(e * BETA + xv, &O4[v]);
            v += 256;
        }
    }

    // ---------- fused reduction: last RED_BLOCKS blocks ----------
    if (FUSED && blk >= GRID1 - RED_BLOCKS) {
        if (tid == 0) {
            // arrivals normally completed ~25us ago; spin is a formality
            while (atomicAdd(cnt, 0u) < (unsigned)GEMM_TILES)
                __builtin_amdgcn_s_sleep(8);
        }
        __syncthreads();
        __threadfence();                  // device-scope acquire (inv stale lines)

        const int t = (blk - (GRID1 - RED_BLOCKS)) * THREADS + tid;  // [0,32768)
        float acc = 0.f;
        #pragma unroll
        for (int k = 0; k < KSPLIT; ++k)
            acc += ws[k * (Bb * D_H) + t];                // fixed order: deterministic
        const float un = BETA * u[t] + acc;
        out[t]            = tanhf(un);    // s
        out[Bb * D_H + t] = un;           // u_new
    }
}

__global__ __launch_bounds__(THREADS) void rtrl_k2(
    const float* __restrict__ ws,  // [KSPLIT][32][1024]
    const float* __restrict__ u,   // [32,1024]
    float* __restrict__ out)       // [s | u_new | ...]
{
    const int t = blockIdx.x * THREADS + threadIdx.x;   // output (b,j), 32768 total
    float acc = 0.f;
    #pragma unroll
    for (int k = 0; k < KSPLIT; ++k)
        acc += ws[k * (Bb * D_H) + t];
    const float un = BETA * u[t] + acc;
    out[t]            = tanhf(un);   // s
    out[Bb * D_H + t] = un;          // u_new
}

extern "C" void kernel_launch(void* const* d_in, const int* in_sizes, int n_in,
                              void* d_out, int out_size, void* d_ws, size_t ws_size,
                              hipStream_t stream) {
    const float* x = (const float*)d_in[0];
    const float* W = (const float*)d_in[1];
    const float* u = (const float*)d_in[2];
    const float* E = (const float*)d_in[3];
    float* out = (float*)d_out;
    float* ws  = (float*)d_ws;     // partials: 4 MB at base

    if (ws_size >= PART_BYTES + sizeof(unsigned)) {
        unsigned* cnt = (unsigned*)((char*)d_ws + PART_BYTES);
        hipMemsetAsync(cnt, 0, sizeof(unsigned), stream);   // per-call reset
        rtrl_k1<true><<<GRID1, THREADS, 0, stream>>>(x, W, u, E, out, ws, cnt);
    } else {
        rtrl_k1<false><<<GRID1, THREADS, 0, stream>>>(x, W, u, E, out, ws, nullptr);
        rtrl_k2<<<(Bb * D_H) / THREADS, THREADS, 0, stream>>>(ws, u, out);
    }
}

// Round 10
// 47.951 us; speedup vs baseline: 1.8732x; 1.7407x over previous
//
#include <hip/hip_runtime.h>
#include <math.h>

// diag-RTRL, round 10: single kernel, intra-block k-split GEMM. No ws, no k2,
// no fences, no grid sync.
//   s      = tanh(0.9*u + x@W)         [32,1024]
//   u_new  = 0.9*u + x@W               [32,1024]
//   E_new  = 0.9*E + x[:,:,None]       [32,1024,1024]  (268 MB stream, dominates)
//
// History: r4 two-kernel split-K = 48.6us best. Fusion via device-scope sync
// failed twice (r8 fences=83us thrash; r9 coop launch errored). r1/r3/r7
// showed narrow GEMM (<=128 blocks) = latency tail. This round: 1024 GEMM
// blocks, each one (b, 32-col j-tile), K=1024 split 8-way ACROSS THE BLOCK'S
// OWN THREADS -> reduction is a 1KB-LDS __syncthreads() reduce (fixed order,
// deterministic), s/u_new written directly. GEMM blocks take 15 E-trips,
// plain blocks 17 (1024*15+1024*17 = 32768 = full E).

#define BETA 0.9f

constexpr int Bb   = 32;
constexpr int D_IN = 1024;
constexpr int D_H  = 1024;

constexpr int THREADS     = 256;
constexpr int GEMM_BLOCKS = 1024;   // (b, j-tile32): 32 x 32
constexpr int GRID        = 2048;
constexpr int TRIPS_G     = 15;     // E trips for GEMM blocks
constexpr int TRIPS_E     = 17;     // E trips for plain blocks

typedef float f4 __attribute__((ext_vector_type(4)));

__global__ __launch_bounds__(THREADS) void rtrl_one(
    const float* __restrict__ x,   // [32,1024]
    const float* __restrict__ W,   // [1024,1024]
    const float* __restrict__ u,   // [32,1024]
    const float* __restrict__ E,   // [32,1024,1024]
    float* __restrict__ out)       // [s | u_new | E_new]
{
    __shared__ float xs[D_IN];     // 4 KB : this block's x row
    __shared__ float part[8][32];  // 1 KB : k-split partials

    const int blk = blockIdx.x;
    const int tid = threadIdx.x;

    if (blk < GEMM_BLOCKS) {
        // ---------- GEMM: b = blk>>5, j-tile = (blk&31)*32, 8-way k-split ----
        const int b  = blk >> 5;
        const int j0 = (blk & 31) * 32;
        const int jc = tid & 31;          // column within tile
        const int ks = tid >> 5;          // k-segment 0..7 (128 rows each)

        // stage x row (4 KB), f4-vectorized cooperative load
        {
            f4* xs4 = (f4*)xs;
            const f4* x4 = (const f4*)(x + b * D_IN);
            if (tid < 256) xs4[tid] = x4[tid];   // 256 f4 = 1024 floats
        }
        __syncthreads();

        // 128 FMAs: W direct (32 lanes consecutive j -> 128B segments;
        // W[:,jtile] reused by 32 b-blocks via L2). 4 indep accumulators.
        const float* __restrict__ Wp = W + (ks * 128) * D_H + j0 + jc;
        const float* __restrict__ xp = xs + ks * 128;
        float a0 = 0.f, a1 = 0.f, a2 = 0.f, a3 = 0.f;
        #pragma unroll 8
        for (int i = 0; i < 128; i += 4) {
            a0 = fmaf(xp[i + 0], Wp[(i + 0) * D_H], a0);
            a1 = fmaf(xp[i + 1], Wp[(i + 1) * D_H], a1);
            a2 = fmaf(xp[i + 2], Wp[(i + 2) * D_H], a2);
            a3 = fmaf(xp[i + 3], Wp[(i + 3) * D_H], a3);
        }
        part[ks][jc] = (a0 + a1) + (a2 + a3);
        __syncthreads();

        // fixed-order 8-way reduce + epilogue by first 32 threads
        if (tid < 32) {
            float acc = part[0][tid];
            #pragma unroll
            for (int k = 1; k < 8; ++k) acc += part[k][tid];
            const int   idx = b * D_H + j0 + tid;
            const float un  = BETA * u[idx] + acc;
            out[idx]            = tanhf(un);   // s
            out[Bb * D_H + idx] = un;          // u_new
        }
    }

    // ---------- E stream: contiguous region per block ----------
    const f4* __restrict__ E4 = (const f4*)E;
    f4* __restrict__ O4 = (f4*)(out + 2 * Bb * D_H);

    const int ntrips = (blk < GEMM_BLOCKS) ? TRIPS_G : TRIPS_E;
    const int r0     = (blk < GEMM_BLOCKS)
                     ? blk * (TRIPS_G * THREADS)
                     : GEMM_BLOCKS * (TRIPS_G * THREADS) + (blk - GEMM_BLOCKS) * (TRIPS_E * THREADS);

    int v = r0 + tid;
    int t = 0;
    for (; t + 4 <= ntrips; t += 4) {     // 4 loads in flight
        f4 e0 = E4[v];
        f4 e1 = E4[v + 256];
        f4 e2 = E4[v + 512];
        f4 e3 = E4[v + 768];
        const float x0 = x[v >> 8];
        const float x1 = x[(v + 256) >> 8];
        const float x2 = x[(v + 512) >> 8];
        const float x3 = x[(v + 768) >> 8];
        __builtin_nontemporal_store(e0 * BETA + x0, &O4[v]);
        __builtin_nontemporal_store(e1 * BETA + x1, &O4[v + 256]);
        __builtin_nontemporal_store(e2 * BETA + x2, &O4[v + 512]);
        __builtin_nontemporal_store(e3 * BETA + x3, &O4[v + 768]);
        v += 1024;
    }
    for (; t < ntrips; ++t) {
        f4 e = E4[v];
        const float xv = x[v >> 8];
        __builtin_nontemporal_store(e * BETA + xv, &O4[v]);
        v += 256;
    }
}

extern "C" void kernel_launch(void* const* d_in, const int* in_sizes, int n_in,
                              void* d_out, int out_size, void* d_ws, size_t ws_size,
                              hipStream_t stream) {
    const float* x = (const float*)d_in[0];
    const float* W = (const float*)d_in[1];
    const float* u = (const float*)d_in[2];
    const float* E = (const float*)d_in[3];
    float* out = (float*)d_out;

    rtrl_one<<<GRID, THREADS, 0, stream>>>(x, W, u, E, out);
}

// Round 11
// 47.755 us; speedup vs baseline: 1.8809x; 1.0041x over previous
//
#include <hip/hip_runtime.h>
#include <math.h>

// diag-RTRL, round 11: r10 structure + {14/18 trip rebalance, SGPR-uniform
// x loads in stream, ILP-8 stream loop (NT stores kept)}.
//   s      = tanh(0.9*u + x@W)         [32,1024]
//   u_new  = 0.9*u + x@W               [32,1024]
//   E_new  = 0.9*E + x[:,:,None]       [32,1024,1024]  (268 MB stream, dominates)
//
// History: r10 single-kernel intra-block-k-split = 47.95us best (r4 two-kernel
// 48.6; all cross-block fusion attempts failed/regressed). Model floor:
// 268 MB logical / 6.29 TB/s copy ceiling = 42.6us. This round attacks the
// remaining 12%: (1) GEMM blocks did 15 trips + ~3 trips of GEMM -> late
// finishers; now 14/18. (2) x[v>>8] was a per-lane VMEM load of a
// block-uniform value; now x[xi+t] with SGPR-only index -> s_load.
// (3) ILP-4 -> ILP-8 (r6's ILP-8 regression was confounded; isolated retest).

#define BETA 0.9f

constexpr int Bb   = 32;
constexpr int D_IN = 1024;
constexpr int D_H  = 1024;

constexpr int THREADS     = 256;
constexpr int GEMM_BLOCKS = 1024;   // (b, j-tile32): 32 x 32
constexpr int GRID        = 2048;
constexpr int TRIPS_G     = 14;     // E trips for GEMM blocks (+ ~3-4 equiv GEMM)
constexpr int TRIPS_E     = 18;     // E trips for plain blocks
// 1024*14 + 1024*18 = 32768 trips * 256 f4 = 8,388,608 f4 = full E.

typedef float f4 __attribute__((ext_vector_type(4)));

__global__ __launch_bounds__(THREADS) void rtrl_one(
    const float* __restrict__ x,   // [32,1024]
    const float* __restrict__ W,   // [1024,1024]
    const float* __restrict__ u,   // [32,1024]
    const float* __restrict__ E,   // [32,1024,1024]
    float* __restrict__ out)       // [s | u_new | E_new]
{
    __shared__ float xs[D_IN];     // 4 KB : this block's x row
    __shared__ float part[8][32];  // 1 KB : k-split partials

    const int blk = blockIdx.x;
    const int tid = threadIdx.x;

    if (blk < GEMM_BLOCKS) {
        // ---------- GEMM: b = blk>>5, j-tile = (blk&31)*32, 8-way k-split ----
        const int b  = blk >> 5;
        const int j0 = (blk & 31) * 32;
        const int jc = tid & 31;          // column within tile
        const int ks = tid >> 5;          // k-segment 0..7 (128 rows each)

        // stage x row (4 KB), f4-vectorized cooperative load
        {
            f4* xs4 = (f4*)xs;
            const f4* x4 = (const f4*)(x + b * D_IN);
            xs4[tid] = x4[tid];           // 256 f4 = 1024 floats
        }
        __syncthreads();

        // 128 FMAs: W direct (32 lanes consecutive j -> 128B segments;
        // W[:,jtile] reused by 32 b-blocks via L2/L3). 4 indep accumulators.
        const float* __restrict__ Wp = W + (ks * 128) * D_H + j0 + jc;
        const float* __restrict__ xp = xs + ks * 128;
        float a0 = 0.f, a1 = 0.f, a2 = 0.f, a3 = 0.f;
        #pragma unroll 8
        for (int i = 0; i < 128; i += 4) {
            a0 = fmaf(xp[i + 0], Wp[(i + 0) * D_H], a0);
            a1 = fmaf(xp[i + 1], Wp[(i + 1) * D_H], a1);
            a2 = fmaf(xp[i + 2], Wp[(i + 2) * D_H], a2);
            a3 = fmaf(xp[i + 3], Wp[(i + 3) * D_H], a3);
        }
        part[ks][jc] = (a0 + a1) + (a2 + a3);
        __syncthreads();

        // fixed-order 8-way reduce + epilogue by first 32 threads
        if (tid < 32) {
            float acc = part[0][tid];
            #pragma unroll
            for (int k = 1; k < 8; ++k) acc += part[k][tid];
            const int   idx = b * D_H + j0 + tid;
            const float un  = BETA * u[idx] + acc;
            out[idx]            = tanhf(un);   // s
            out[Bb * D_H + idx] = un;          // u_new
        }
    }

    // ---------- E stream: contiguous region per block ----------
    const f4* __restrict__ E4 = (const f4*)E;
    f4* __restrict__ O4 = (f4*)(out + 2 * Bb * D_H);

    const int ntrips = (blk < GEMM_BLOCKS) ? TRIPS_G : TRIPS_E;
    // xi = global trip index base: pure SGPR arithmetic, block-uniform.
    const int xi     = (blk < GEMM_BLOCKS)
                     ? blk * TRIPS_G
                     : GEMM_BLOCKS * TRIPS_G + (blk - GEMM_BLOCKS) * TRIPS_E;

    int v = xi * THREADS + tid;
    int t = 0;
    for (; t + 8 <= ntrips; t += 8) {     // 8 loads in flight
        f4 e[8];
        #pragma unroll
        for (int j = 0; j < 8; ++j) e[j] = E4[v + j * 256];
        float xv[8];
        #pragma unroll
        for (int j = 0; j < 8; ++j) xv[j] = x[xi + t + j];   // SGPR index -> s_load
        #pragma unroll
        for (int j = 0; j < 8; ++j)
            __builtin_nontemporal_store(e[j] * BETA + xv[j], &O4[v + j * 256]);
        v += 8 * 256;
    }
    for (; t + 4 <= ntrips; t += 4) {
        f4 e[4];
        #pragma unroll
        for (int j = 0; j < 4; ++j) e[j] = E4[v + j * 256];
        float xv[4];
        #pragma unroll
        for (int j = 0; j < 4; ++j) xv[j] = x[xi + t + j];
        #pragma unroll
        for (int j = 0; j < 4; ++j)
            __builtin_nontemporal_store(e[j] * BETA + xv[j], &O4[v + j * 256]);
        v += 4 * 256;
    }
    for (; t < ntrips; ++t) {
        f4 e = E4[v];
        const float xv = x[xi + t];
        __builtin_nontemporal_store(e * BETA + xv, &O4[v]);
        v += 256;
    }
}

extern "C" void kernel_launch(void* const* d_in, const int* in_sizes, int n_in,
                              void* d_out, int out_size, void* d_ws, size_t ws_size,
                              hipStream_t stream) {
    const float* x = (const float*)d_in[0];
    const float* W = (const float*)d_in[1];
    const float* u = (const float*)d_in[2];
    const float* E = (const float*)d_in[3];
    float* out = (float*)d_out;

    rtrl_one<<<GRID, THREADS, 0, stream>>>(x, W, u, E, out);
}